// Round 2
// baseline (2085.101 us; speedup 1.0000x reference)
//
#include <hip/hip_runtime.h>
#include <math.h>

#define BB 16
#define NN 8192
#define DD 768
#define NSLOTS 24
#define EPSF 1e-12f

// ---------------------------------------------------------------------------
// Kernel 1: per-row norm -> saliency, inv_norm, mask=1
// One wave (64 lanes) per row; 4 rows per 256-thread block.
// Row = 768 floats = 192 float4; lane reads float4 at {lane, lane+64, lane+128}.
// ---------------------------------------------------------------------------
__global__ __launch_bounds__(256) void k_init(const float* __restrict__ feat,
                                              float* __restrict__ sal,
                                              float* __restrict__ inv,
                                              float* __restrict__ mask) {
    const int wave = threadIdx.x >> 6;
    const int lane = threadIdx.x & 63;
    const long row = (long)blockIdx.x * 4 + wave;   // < BB*NN
    const float4* fr = (const float4*)(feat + row * DD);
    float acc = 0.f;
#pragma unroll
    for (int i = 0; i < 3; ++i) {
        float4 v = fr[lane + i * 64];
        acc = fmaf(v.x, v.x, acc);
        acc = fmaf(v.y, v.y, acc);
        acc = fmaf(v.z, v.z, acc);
        acc = fmaf(v.w, v.w, acc);
    }
#pragma unroll
    for (int off = 32; off; off >>= 1) acc += __shfl_xor(acc, off);
    if (lane == 0) {
        float nrm = sqrtf(acc);
        sal[row]  = nrm;                      // saliency_mode == 'norm'
        inv[row]  = 1.f / fmaxf(nrm, EPSF);
        mask[row] = 1.f;
    }
}

// ---------------------------------------------------------------------------
// Kernel 2: per-batch argmax over saliency*mask (first-occurrence semantics),
// then load the selected row, compute its norm, write output slot and the
// scaled selected vector (selected / max(||selected||, eps)).
// One block of 1024 threads per batch.
// ---------------------------------------------------------------------------
__global__ __launch_bounds__(1024) void k_select(const float* __restrict__ feat,
                                                 const float* __restrict__ sal,
                                                 const float* __restrict__ mask,
                                                 float* __restrict__ selv,
                                                 float* __restrict__ out,
                                                 int s) {
    const int b = blockIdx.x;
    const int t = threadIdx.x;
    __shared__ float svals[1024];
    __shared__ int   sidx[1024];

    const float* salb = sal  + (long)b * NN;
    const float* mb   = mask + (long)b * NN;

    // thread-local scan in increasing n: strict '>' keeps first occurrence
    float best = -1.f;
    int bidx = 0;
#pragma unroll
    for (int k = 0; k < NN / 1024; ++k) {
        int n = t + k * 1024;
        float v = salb[n] * mb[n];
        if (v > best) { best = v; bidx = n; }
    }
    svals[t] = best;
    sidx[t]  = bidx;
    __syncthreads();
    for (int stride = 512; stride; stride >>= 1) {
        if (t < stride) {
            float v2 = svals[t + stride];
            int   i2 = sidx[t + stride];
            if (v2 > svals[t] || (v2 == svals[t] && i2 < sidx[t])) {
                svals[t] = v2;
                sidx[t]  = i2;
            }
        }
        __syncthreads();
    }
    const int idx = sidx[0];

    // selected row: norm + writes
    __shared__ float ssum[1024];
    float f = 0.f;
    if (t < DD) f = feat[((long)b * NN + idx) * DD + t];
    ssum[t] = f * f;
    __syncthreads();
    for (int stride = 512; stride; stride >>= 1) {
        if (t < stride) ssum[t] += ssum[t + stride];
        __syncthreads();
    }
    const float nrm  = sqrtf(ssum[0]);
    const float invs = 1.f / fmaxf(nrm, EPSF);
    if (t < DD) {
        out[((long)b * NSLOTS + s) * DD + t] = f;   // aggregate=False: raw feature
        selv[b * DD + t] = f * invs;                // sel_norm
    }
}

// ---------------------------------------------------------------------------
// Kernel 3: mask update. One wave per row: sim = dot(feat_row, selv_b)*inv[row];
// mask *= 1 - clamp(sim, 0, 1). Reads all of `feat` (the 402 MB pass).
// ---------------------------------------------------------------------------
__global__ __launch_bounds__(256) void k_update(const float* __restrict__ feat,
                                                const float* __restrict__ selv,
                                                const float* __restrict__ inv,
                                                float* __restrict__ mask) {
    const int wave = threadIdx.x >> 6;
    const int lane = threadIdx.x & 63;
    const long row = (long)blockIdx.x * 4 + wave;
    const int b = (int)(row >> 13);                 // NN = 8192 = 2^13
    const float4* fr = (const float4*)(feat + row * DD);
    const float4* sv = (const float4*)(selv + (long)b * DD);
    float acc = 0.f;
#pragma unroll
    for (int i = 0; i < 3; ++i) {
        float4 v = fr[lane + i * 64];
        float4 s = sv[lane + i * 64];
        acc = fmaf(v.x, s.x, acc);
        acc = fmaf(v.y, s.y, acc);
        acc = fmaf(v.z, s.z, acc);
        acc = fmaf(v.w, s.w, acc);
    }
#pragma unroll
    for (int off = 32; off; off >>= 1) acc += __shfl_xor(acc, off);
    if (lane == 0) {
        float sim = acc * inv[row];
        sim = fminf(fmaxf(sim, 0.f), 1.f);
        mask[row] *= (1.f - sim);
    }
}

extern "C" void kernel_launch(void* const* d_in, const int* in_sizes, int n_in,
                              void* d_out, int out_size, void* d_ws, size_t ws_size,
                              hipStream_t stream) {
    // d_in[0] = batch_size (int scalar, ignored: shapes fixed by setup_inputs)
    // d_in[1] = features [16, 8192, 768] fp32
    const float* feat = (const float*)d_in[1];
    float* out = (float*)d_out;

    float* sal  = (float*)d_ws;            // B*N fp32
    float* inv  = sal  + BB * NN;          // B*N fp32
    float* mask = inv  + BB * NN;          // B*N fp32
    float* selv = mask + BB * NN;          // B*D fp32
    // total ws use: 3*16*8192*4 + 16*768*4 bytes ~= 1.6 MB

    const int rows = BB * NN;
    k_init<<<rows / 4, 256, 0, stream>>>(feat, sal, inv, mask);
    for (int s = 0; s < NSLOTS; ++s) {
        k_select<<<BB, 1024, 0, stream>>>(feat, sal, mask, selv, out, s);
        if (s < NSLOTS - 1) {
            k_update<<<rows / 4, 256, 0, stream>>>(feat, selv, inv, mask);
        }
    }
}